// Round 16
// baseline (277.136 us; speedup 1.0000x reference)
//
#include <hip/hip_runtime.h>
#include <hip/hip_bf16.h>

typedef __attribute__((ext_vector_type(8))) short short8;
typedef __attribute__((ext_vector_type(4))) float f32x4;
typedef __attribute__((ext_vector_type(4))) unsigned uintx4;

#define B_  32
#define S_  484
#define E_  1024
#define NH  16
#define SP  512          // padded sequence length
#define M_  (B_*S_)      // 15488

static __device__ __forceinline__ ushort f2bf(float f) {
  union { float f; unsigned u; } v; v.f = f;
  unsigned u = v.u;
  return (ushort)((u + 0x7FFFu + ((u >> 16) & 1u)) >> 16);
}

static __device__ __forceinline__ unsigned cvt_pk_bf16(float lo, float hi) {
  unsigned r;
  asm("v_cvt_pk_bf16_f32 %0, %1, %2" : "=v"(r) : "v"(lo), "v"(hi));
  return r;
}

#define GLOAD_LDS16(gp, lp) \
  __builtin_amdgcn_global_load_lds((const __attribute__((address_space(1))) void*)(gp), \
                                   (__attribute__((address_space(3))) void*)(lp), 16, 0, 0)

// ---------------- all 4 weight transposes in one launch ----------------
__global__ __launch_bounds__(256)
void transpose_all(const float* __restrict__ Wq, const float* __restrict__ Wk,
                   const float* __restrict__ Wv, const float* __restrict__ Wo,
                   ushort* __restrict__ wqT, ushort* __restrict__ wkT,
                   ushort* __restrict__ wvT, ushort* __restrict__ woT) {
  __shared__ float tile[32][33];
  int t = blockIdx.x;
  const float* W; ushort* WT; int N;
  if (t < 1024)      { W = Wq; WT = wqT; N = 1024; }
  else if (t < 1280) { W = Wk; WT = wkT; N = 256;  t -= 1024; }
  else if (t < 1536) { W = Wv; WT = wvT; N = 256;  t -= 1280; }
  else               { W = Wo; WT = woT; N = 1024; t -= 1536; }
  const int nx = N >> 5;
  const int n0 = (t % nx) * 32, k0 = (t / nx) * 32;
  const int tx = threadIdx.x & 31, ty = threadIdx.x >> 5;   // 32 x 8
  for (int i = ty; i < 32; i += 8) tile[i][tx] = W[(size_t)(k0 + i) * N + n0 + tx];
  __syncthreads();
  for (int i = ty; i < 32; i += 8) WT[(size_t)(n0 + i) * 1024 + k0 + tx] = f2bf(tile[tx][i]);
}

// ======== counted-vmcnt GEMM: 256x256 tile, 512 thr, 4-buffer depth-3 (O-proj) ========
template<int EPI>
__global__ __launch_bounds__(512)
void gemm_cnt256(const ushort* __restrict__ A, const ushort* __restrict__ BT,
                 void* __restrict__ Cout, float oscale) {
  const int K = 1024, N = 1024, NK = 32;
  __shared__ alignas(16) ushort sA[4][256 * 32];
  __shared__ alignas(16) ushort sB[4][256 * 32];
  const int tid = threadIdx.x;
  const int lane = tid & 63, w = tid >> 6;        // 8 waves

  const int nwg = gridDim.x;
  const int qq = nwg >> 3, rr = nwg & 7;
  const int x = blockIdx.x & 7, seq = blockIdx.x >> 3;
  const int logical = x * qq + (x < rr ? x : rr) + seq;
  const int m0 = (logical >> 2) * 256;            // 61 m-tiles
  const int n0 = (logical & 3) * 256;             // 4 n-tiles

  const int brow = tid >> 2;
  const int scol = (((tid & 3) ^ ((tid >> 3) & 3))) * 8;
  const int rowA0 = min(m0 + brow, M_ - 1);
  const int rowA1 = min(m0 + brow + 128, M_ - 1);
  const ushort* gA0 = A + (size_t)rowA0 * K + scol;
  const ushort* gA1 = A + (size_t)rowA1 * K + scol;
  const ushort* gB0 = BT + (size_t)(n0 + brow) * K + scol;
  const int dst = tid * 8;

  const int wr = w >> 2, wc = w & 3;              // 2x4 wave grid, each 128x64
  const int g4 = lane >> 4, l16 = lane & 15;
  const int rs = (l16 >> 1) & 3;

  f32x4 acc[8][4] = {};

  auto stage = [&](int kt, int buf) {
    GLOAD_LDS16(gA0 + kt * 32,           &sA[buf][dst]);
    GLOAD_LDS16(gA1 + kt * 32,           &sA[buf][dst + 4096]);
    GLOAD_LDS16(gB0 + kt * 32,           &sB[buf][dst]);
    GLOAD_LDS16(gB0 + kt * 32 + 128 * K, &sB[buf][dst + 4096]);
  };

  stage(0, 0);
  stage(1, 1);
  stage(2, 2);

  int cur = 0;
  for (int kt = 0; kt < NK; ++kt) {
    if (kt < NK - 2)       asm volatile("s_waitcnt vmcnt(8)" ::: "memory");
    else if (kt == NK - 2) asm volatile("s_waitcnt vmcnt(4)" ::: "memory");
    else                   asm volatile("s_waitcnt vmcnt(0)" ::: "memory");
    asm volatile("s_waitcnt lgkmcnt(0)" ::: "memory");
    __builtin_amdgcn_s_barrier();
    if (kt + 3 < NK) stage(kt + 3, (cur + 3) & 3);
    const ushort* pa = &sA[cur][(wr * 128 + l16) * 32 + 8 * (g4 ^ rs)];
    const ushort* pb = &sB[cur][(wc * 64 + l16) * 32 + 8 * (g4 ^ rs)];
    short8 af[8], bf[4];
#pragma unroll
    for (int i = 0; i < 8; ++i) af[i] = *(const short8*)(pa + i * 16 * 32);
#pragma unroll
    for (int i = 0; i < 4; ++i) bf[i] = *(const short8*)(pb + i * 16 * 32);
#pragma unroll
    for (int mi = 0; mi < 8; ++mi)
#pragma unroll
      for (int ni = 0; ni < 4; ++ni)
        acc[mi][ni] = __builtin_amdgcn_mfma_f32_16x16x32_bf16(af[mi], bf[ni], acc[mi][ni], 0, 0, 0);
    cur = (cur + 1) & 3;
  }

#pragma unroll
  for (int mi = 0; mi < 8; ++mi) {
#pragma unroll
    for (int ni = 0; ni < 4; ++ni) {
#pragma unroll
      for (int r = 0; r < 4; ++r) {
        int m = m0 + wr * 128 + mi * 16 + g4 * 4 + r;
        int n = n0 + wc * 64 + ni * 16 + l16;
        if (m < M_) {
          float vv = acc[mi][ni][r];
          if (EPI == 2) {
            ((float*)Cout)[(size_t)m * N + n] = vv;
          } else {
            int b = m / S_, pos = m % S_;
            ushort hv = f2bf(vv * oscale);
            ((ushort*)Cout)[(((size_t)b * NH + (n >> 6)) * SP + pos) * 64 + (n & 63)] = hv;
          }
        }
      }
    }
  }
}

// ======== Q projection: 256m x 128n, counted-vmcnt depth-3, f32-A (fused cvt) ========
// Clone of the proven kvproj256 structure. Grid 488 = 61 m-tiles x 8 n-subs;
// chunked-XCD map co-locates the 8 sharers of each query m-slab on one XCD.
__global__ __launch_bounds__(512, 2)
void qproj256(const float* __restrict__ query, const ushort* __restrict__ BT,
              ushort* __restrict__ qp, float oscale) {
  const int K = 1024, NK = 32;
  __shared__ alignas(16) ushort sA[4][256 * 32];   // 64 KB
  __shared__ alignas(16) ushort sB[4][128 * 32];   // 32 KB
  const int tid = threadIdx.x;
  const int lane = tid & 63, w = tid >> 6;         // 8 waves

  const int nwg = gridDim.x;                       // 488: qq=61, rr=0
  const int qq = nwg >> 3, rr = nwg & 7;
  const int x = blockIdx.x & 7, seq = blockIdx.x >> 3;
  const int logical = x * qq + (x < rr ? x : rr) + seq;
  const int m0 = (logical >> 3) * 256;             // 61 m-tiles
  const int sub = logical & 7;
  const int n0g = sub * 128;

  const int brow = tid >> 2;
  const int scol = (((tid & 3) ^ ((tid >> 3) & 3))) * 8;
  const ushort* gB0 = BT + (size_t)(n0g + brow) * K + scol;
  const int dstB = tid * 8;

  const int arow = tid >> 1;
  const int rowAf = min(m0 + arow, M_ - 1);
  const float* gAf = query + (size_t)rowAf * K + (tid & 1) * 16;
  const int sw = (arow >> 1) & 3;
  const int ag0 = (2 * (tid & 1)) ^ sw;
  const int ag1 = (2 * (tid & 1) + 1) ^ sw;

  const int wr = w >> 1, wc = w & 1;               // 4x2 wave grid, each 64x64
  const int g4 = lane >> 4, l16 = lane & 15;
  const int rs = (l16 >> 1) & 3;

  f32x4 acc[4][4] = {};
  float4 fA[3][4];

  auto stageB = [&](int kt) {
    GLOAD_LDS16(gB0 + kt * 32, &sB[kt & 3][dstB]);
  };
  auto compute = [&](int kt) {
    const int buf = kt & 3;
    const ushort* pa = &sA[buf][(wr * 64 + l16) * 32 + 8 * (g4 ^ rs)];
    const ushort* pb = &sB[buf][(wc * 64 + l16) * 32 + 8 * (g4 ^ rs)];
    short8 af[4], bf[4];
#pragma unroll
    for (int i = 0; i < 4; ++i) {
      af[i] = *(const short8*)(pa + i * 16 * 32);
      bf[i] = *(const short8*)(pb + i * 16 * 32);
    }
#pragma unroll
    for (int mi = 0; mi < 4; ++mi)
#pragma unroll
      for (int ni = 0; ni < 4; ++ni)
        acc[mi][ni] = __builtin_amdgcn_mfma_f32_16x16x32_bf16(af[mi], bf[ni], acc[mi][ni], 0, 0, 0);
  };

#define ISSUEA(kt, slot) do { \
    const float4* _p = (const float4*)(gAf + (kt) * 32); \
    fA[slot][0] = _p[0]; fA[slot][1] = _p[1]; fA[slot][2] = _p[2]; fA[slot][3] = _p[3]; \
  } while (0)
#define WRITEA(kt, slot) do { \
    unsigned _d0 = cvt_pk_bf16(fA[slot][0].x, fA[slot][0].y), _d1 = cvt_pk_bf16(fA[slot][0].z, fA[slot][0].w); \
    unsigned _d2 = cvt_pk_bf16(fA[slot][1].x, fA[slot][1].y), _d3 = cvt_pk_bf16(fA[slot][1].z, fA[slot][1].w); \
    unsigned _d4 = cvt_pk_bf16(fA[slot][2].x, fA[slot][2].y), _d5 = cvt_pk_bf16(fA[slot][2].z, fA[slot][2].w); \
    unsigned _d6 = cvt_pk_bf16(fA[slot][3].x, fA[slot][3].y), _d7 = cvt_pk_bf16(fA[slot][3].z, fA[slot][3].w); \
    ushort* _base = &sA[(kt) & 3][arow * 32]; \
    uintx4 _q0 = {_d0, _d1, _d2, _d3}, _q1 = {_d4, _d5, _d6, _d7}; \
    *(uintx4*)(_base + ag0 * 8) = _q0; \
    *(uintx4*)(_base + ag1 * 8) = _q1; \
  } while (0)
#define KSTEP(kt, ws, is) do { \
    if ((kt) < NK - 2) asm volatile("s_waitcnt vmcnt(5)" ::: "memory"); \
    else               asm volatile("s_waitcnt vmcnt(0)" ::: "memory"); \
    if ((kt) + 1 < NK) WRITEA((kt) + 1, ws); \
    asm volatile("s_waitcnt lgkmcnt(0)" ::: "memory"); \
    __builtin_amdgcn_s_barrier(); \
    if ((kt) + 3 < NK) { stageB((kt) + 3); ISSUEA((kt) + 3, is); } \
    compute(kt); \
  } while (0)

  stageB(0); ISSUEA(0, 0);
  stageB(1); ISSUEA(1, 1);
  stageB(2); ISSUEA(2, 2);
  asm volatile("s_waitcnt vmcnt(10)" ::: "memory");
  WRITEA(0, 0);

  for (int kb = 0; kb < 30; kb += 3) {
    KSTEP(kb,     1, 0);
    KSTEP(kb + 1, 2, 1);
    KSTEP(kb + 2, 0, 2);
  }
  KSTEP(30, 1, 0);
  KSTEP(31, 0, 0);

#undef KSTEP
#undef WRITEA
#undef ISSUEA

#pragma unroll
  for (int mi = 0; mi < 4; ++mi) {
#pragma unroll
    for (int ni = 0; ni < 4; ++ni) {
#pragma unroll
      for (int r = 0; r < 4; ++r) {
        int m = m0 + wr * 64 + mi * 16 + g4 * 4 + r;
        int n = n0g + wc * 64 + ni * 16 + l16;
        if (m < M_) {
          int b = m / S_, pos = m % S_;
          ushort hv = f2bf(acc[mi][ni][r] * oscale);
          qp[(((size_t)b * NH + (n >> 6)) * SP + pos) * 64 + (n & 63)] = hv;
        }
      }
    }
  }
}

// ======== K+V projections: 256m x 128n tiles, counted-vmcnt depth-3, f32-A ========
// (R14-proven version, exact)
__global__ __launch_bounds__(512, 2)
void kvproj256(const float* __restrict__ key, const float* __restrict__ value,
               const ushort* __restrict__ BT,
               ushort* __restrict__ kp, ushort* __restrict__ vp) {
  const int K = 1024, NK = 32;
  __shared__ alignas(16) ushort sA[4][256 * 32];   // 64 KB
  __shared__ alignas(16) ushort sB[4][128 * 32];   // 32 KB
  const int tid = threadIdx.x;
  const int lane = tid & 63, w = tid >> 6;         // 8 waves

  const int nwg = gridDim.x;                       // 244: qq=30, rr=4
  const int qq = nwg >> 3, rr = nwg & 7;
  const int x = blockIdx.x & 7, seq = blockIdx.x >> 3;
  const int logical = x * qq + (x < rr ? x : rr) + seq;
  const int m0 = (logical >> 2) * 256;             // 61 m-tiles
  const int sub = logical & 3;
  const bool isV = sub >= 2;
  const int n0l = (sub & 1) * 128;
  const float* Ain = isV ? value : key;

  const int brow = tid >> 2;
  const int scol = (((tid & 3) ^ ((tid >> 3) & 3))) * 8;
  const ushort* gB0 = BT + (size_t)((isV ? 256 : 0) + n0l + brow) * K + scol;
  const int dstB = tid * 8;

  const int arow = tid >> 1;
  const int rowAf = min(m0 + arow, M_ - 1);
  const float* gAf = Ain + (size_t)rowAf * K + (tid & 1) * 16;
  const int sw = (arow >> 1) & 3;
  const int ag0 = (2 * (tid & 1)) ^ sw;
  const int ag1 = (2 * (tid & 1) + 1) ^ sw;

  const int wr = w >> 1, wc = w & 1;               // 4x2 wave grid, each 64x64
  const int g4 = lane >> 4, l16 = lane & 15;
  const int rs = (l16 >> 1) & 3;

  f32x4 acc[4][4] = {};
  float4 fA[3][4];

  auto stageB = [&](int kt) {
    GLOAD_LDS16(gB0 + kt * 32, &sB[kt & 3][dstB]);
  };
  auto compute = [&](int kt) {
    const int buf = kt & 3;
    const ushort* pa = &sA[buf][(wr * 64 + l16) * 32 + 8 * (g4 ^ rs)];
    const ushort* pb = &sB[buf][(wc * 64 + l16) * 32 + 8 * (g4 ^ rs)];
    short8 af[4], bf[4];
#pragma unroll
    for (int i = 0; i < 4; ++i) {
      af[i] = *(const short8*)(pa + i * 16 * 32);
      bf[i] = *(const short8*)(pb + i * 16 * 32);
    }
#pragma unroll
    for (int mi = 0; mi < 4; ++mi)
#pragma unroll
      for (int ni = 0; ni < 4; ++ni)
        acc[mi][ni] = __builtin_amdgcn_mfma_f32_16x16x32_bf16(af[mi], bf[ni], acc[mi][ni], 0, 0, 0);
  };

#define ISSUEA(kt, slot) do { \
    const float4* _p = (const float4*)(gAf + (kt) * 32); \
    fA[slot][0] = _p[0]; fA[slot][1] = _p[1]; fA[slot][2] = _p[2]; fA[slot][3] = _p[3]; \
  } while (0)
#define WRITEA(kt, slot) do { \
    unsigned _d0 = cvt_pk_bf16(fA[slot][0].x, fA[slot][0].y), _d1 = cvt_pk_bf16(fA[slot][0].z, fA[slot][0].w); \
    unsigned _d2 = cvt_pk_bf16(fA[slot][1].x, fA[slot][1].y), _d3 = cvt_pk_bf16(fA[slot][1].z, fA[slot][1].w); \
    unsigned _d4 = cvt_pk_bf16(fA[slot][2].x, fA[slot][2].y), _d5 = cvt_pk_bf16(fA[slot][2].z, fA[slot][2].w); \
    unsigned _d6 = cvt_pk_bf16(fA[slot][3].x, fA[slot][3].y), _d7 = cvt_pk_bf16(fA[slot][3].z, fA[slot][3].w); \
    ushort* _base = &sA[(kt) & 3][arow * 32]; \
    uintx4 _q0 = {_d0, _d1, _d2, _d3}, _q1 = {_d4, _d5, _d6, _d7}; \
    *(uintx4*)(_base + ag0 * 8) = _q0; \
    *(uintx4*)(_base + ag1 * 8) = _q1; \
  } while (0)
#define KSTEP(kt, ws, is) do { \
    if ((kt) < NK - 2) asm volatile("s_waitcnt vmcnt(5)" ::: "memory"); \
    else               asm volatile("s_waitcnt vmcnt(0)" ::: "memory"); \
    if ((kt) + 1 < NK) WRITEA((kt) + 1, ws); \
    asm volatile("s_waitcnt lgkmcnt(0)" ::: "memory"); \
    __builtin_amdgcn_s_barrier(); \
    if ((kt) + 3 < NK) { stageB((kt) + 3); ISSUEA((kt) + 3, is); } \
    compute(kt); \
  } while (0)

  stageB(0); ISSUEA(0, 0);
  stageB(1); ISSUEA(1, 1);
  stageB(2); ISSUEA(2, 2);
  asm volatile("s_waitcnt vmcnt(10)" ::: "memory");
  WRITEA(0, 0);

  for (int kb = 0; kb < 30; kb += 3) {
    KSTEP(kb,     1, 0);
    KSTEP(kb + 1, 2, 1);
    KSTEP(kb + 2, 0, 2);
  }
  KSTEP(30, 1, 0);
  KSTEP(31, 0, 0);

#undef KSTEP
#undef WRITEA
#undef ISSUEA

#pragma unroll
  for (int mi = 0; mi < 4; ++mi) {
#pragma unroll
    for (int ni = 0; ni < 4; ++ni) {
#pragma unroll
      for (int r = 0; r < 4; ++r) {
        int m = m0 + wr * 64 + mi * 16 + g4 * 4 + r;
        int nl = n0l + wc * 64 + ni * 16 + l16;
        if (m < M_) {
          float vv = acc[mi][ni][r];
          int b = m / S_, pos = m % S_;
          int h = nl >> 6, d = nl & 63;
          if (!isV) {
            int dd = d ^ ((pos & 7) << 3);           // K-LDS row bank swizzle
            kp[(((size_t)b * 4 + h) * SP + pos) * 64 + dd] = f2bf(vv);
          } else {
            int local = pos & 31;                    // sigma permute + granule xor
            int j = (local < 16) ? (2 * local) : (2 * local - 31);
            int pf_ = (pos & ~31) | (j ^ ((d & 3) << 3));
            vp[(((size_t)b * 4 + h) * 64 + d) * SP + pf_] = f2bf(vv);
          }
        }
      }
    }
  }
}

// ---------------- fused GQA attention: 32 q-rows per wave, shared K/V frags ----------------
// (R14-proven version, exact)
__global__ __launch_bounds__(256)
void attn_kernel(const ushort* __restrict__ qp, const ushort* __restrict__ kp,
                 const ushort* __restrict__ vpT, const float* __restrict__ rel,
                 ushort* __restrict__ ao) {
  __shared__ float2 sBiasP[1056];                 // (b[i], b[i+16]) pairs, +32 guard
  __shared__ alignas(16) ushort sK[2][32 * 64];
  __shared__ alignas(16) ushort sV[2][64 * 32];
  __shared__ alignas(16) ushort sP[4][32 * 40];
  const int tid = threadIdx.x;
  const int blk = blockIdx.x;
  const int logical = (blk & 7) * 256 + (blk >> 3);     // bijective (2048 = 8*256)
  const int qt = logical & 3, head = (logical >> 2) & 15, b = logical >> 6;
  const int g = head >> 2;
  const float LOG2E = 1.44269504f;
  for (int t = tid; t < 1056; t += 256) {
    float b0 = (t >= 32 && t < 999) ? rel[(t - 32) * 16 + head] * LOG2E : -1e30f;
    int t2 = t + 16;
    float b1 = (t2 >= 32 && t2 < 999) ? rel[(t2 - 32) * 16 + head] * LOG2E : -1e30f;
    sBiasP[t] = make_float2(b0, b1);
  }

  const int lane = tid & 63, w = tid >> 6;
  const int g4 = lane >> 4, l16 = lane & 15;
  const int qw = qt * 128 + w * 32;

  const ushort* qbA = qp + (((size_t)b * NH + head) * SP + qw + l16) * 64;
  const ushort* qbB = qbA + 16 * 64;
  short8 qf0a = *(const short8*)(qbA + 8 * g4);
  short8 qf1a = *(const short8*)(qbA + 32 + 8 * g4);
  short8 qf0b = *(const short8*)(qbB + 8 * g4);
  short8 qf1b = *(const short8*)(qbB + 32 + 8 * g4);

  const ushort* kSrc = kp  + ((size_t)b * 4 + g) * SP * 64 + (tid >> 3) * 64 + (tid & 7) * 8;
  const ushort* vSrc = vpT + ((size_t)b * 4 + g) * 64 * SP + (tid >> 2) * SP + (tid & 3) * 8;

  f32x4 accA[4] = {}, accB[4] = {};
  float psA[4] = {0.f, 0.f, 0.f, 0.f}, psB[4] = {0.f, 0.f, 0.f, 0.f};
  const int ibA = l16 - (qw + g4 * 4) + 515;      // pair-table idx (guard +32)
  const int ibB = ibA - 16;
  ushort* sPw = &sP[w][0];

  const int kswz  = (l16 & 7) << 3;
  const int kOff0 = l16 * 64 + ((8 * g4) ^ kswz);
  const int kOff1 = l16 * 64 + ((32 + 8 * g4) ^ kswz);
  const int vOff  = l16 * 32 + 8 * (g4 ^ (l16 & 3));

  GLOAD_LDS16(kSrc, &sK[0][w * 512]);
  GLOAD_LDS16(vSrc, &sV[0][w * 512]);

  for (int kt = 0; kt < 16; ++kt) {
    __syncthreads();
    if (kt + 1 < 16) {
      GLOAD_LDS16(kSrc + (kt + 1) * 2048, &sK[(kt + 1) & 1][w * 512]);
      GLOAD_LDS16(vSrc + (kt + 1) * 32,   &sV[(kt + 1) & 1][w * 512]);
    }
    const int k0 = kt * 32;
    float2 a0 = sBiasP[ibA + k0],     a1 = sBiasP[ibA + k0 - 1];
    float2 a2 = sBiasP[ibA + k0 - 2], a3 = sBiasP[ibA + k0 - 3];
    float2 c0 = sBiasP[ibB + k0],     c1 = sBiasP[ibB + k0 - 1];
    float2 c2 = sBiasP[ibB + k0 - 2], c3 = sBiasP[ibB + k0 - 3];
    f32x4 s0a = {a0.x, a1.x, a2.x, a3.x}, s1a = {a0.y, a1.y, a2.y, a3.y};
    f32x4 s0b = {c0.x, c1.x, c2.x, c3.x}, s1b = {c0.y, c1.y, c2.y, c3.y};

    const ushort* sk = &sK[kt & 1][0];
    const ushort* sv = &sV[kt & 1][0];
    short8 kf0 = *(const short8*)(sk + kOff0);
    short8 kf1 = *(const short8*)(sk + kOff1);
    short8 kf2 = *(const short8*)(sk + 1024 + kOff0);
    short8 kf3 = *(const short8*)(sk + 1024 + kOff1);
    s0a = __builtin_amdgcn_mfma_f32_16x16x32_bf16(qf0a, kf0, s0a, 0, 0, 0);
    s0a = __builtin_amdgcn_mfma_f32_16x16x32_bf16(qf1a, kf1, s0a, 0, 0, 0);
    s1a = __builtin_amdgcn_mfma_f32_16x16x32_bf16(qf0a, kf2, s1a, 0, 0, 0);
    s1a = __builtin_amdgcn_mfma_f32_16x16x32_bf16(qf1a, kf3, s1a, 0, 0, 0);
    s0b = __builtin_amdgcn_mfma_f32_16x16x32_bf16(qf0b, kf0, s0b, 0, 0, 0);
    s0b = __builtin_amdgcn_mfma_f32_16x16x32_bf16(qf1b, kf1, s0b, 0, 0, 0);
    s1b = __builtin_amdgcn_mfma_f32_16x16x32_bf16(qf0b, kf2, s1b, 0, 0, 0);
    s1b = __builtin_amdgcn_mfma_f32_16x16x32_bf16(qf1b, kf3, s1b, 0, 0, 0);

#pragma unroll
    for (int r = 0; r < 4; ++r) {
      float p0 = __builtin_amdgcn_exp2f(s0a[r]);
      float p1 = __builtin_amdgcn_exp2f(s1a[r]);
      float u0 = __builtin_amdgcn_exp2f(s0b[r]);
      float u1 = __builtin_amdgcn_exp2f(s1b[r]);
      if (kt == 15) {
        bool m0v = (k0 + l16 < S_), m1v = (k0 + 16 + l16 < S_);
        p0 = m0v ? p0 : 0.f;  p1 = m1v ? p1 : 0.f;
        u0 = m0v ? u0 : 0.f;  u1 = m1v ? u1 : 0.f;
      }
      psA[r] += p0 + p1;
      psB[r] += u0 + u1;
      *(unsigned*)(sPw + (g4 * 4 + r) * 40 + 2 * l16)        = cvt_pk_bf16(p0, p1);
      *(unsigned*)(sPw + (16 + g4 * 4 + r) * 40 + 2 * l16)   = cvt_pk_bf16(u0, u1);
    }
    short8 pfA = *(const short8*)(sPw + l16 * 40 + 8 * g4);
    short8 pfB = *(const short8*)(sPw + (16 + l16) * 40 + 8 * g4);
#pragma unroll
    for (int nt = 0; nt < 4; ++nt) {
      short8 vf = *(const short8*)(sv + vOff + nt * 512);    // shared by both sub-tiles
      accA[nt] = __builtin_amdgcn_mfma_f32_16x16x32_bf16(pfA, vf, accA[nt], 0, 0, 0);
      accB[nt] = __builtin_amdgcn_mfma_f32_16x16x32_bf16(pfB, vf, accB[nt], 0, 0, 0);
    }
  }

#pragma unroll
  for (int off = 1; off < 16; off <<= 1) {
#pragma unroll
    for (int r = 0; r < 4; ++r) {
      psA[r] += __shfl_xor(psA[r], off, 64);
      psB[r] += __shfl_xor(psB[r], off, 64);
    }
  }

#pragma unroll
  for (int r = 0; r < 4; ++r) {
    int qa = qw + g4 * 4 + r;
    if (qa < S_) {
      float inv = 1.f / psA[r];
#pragma unroll
      for (int nt = 0; nt < 4; ++nt)
        ao[((size_t)b * S_ + qa) * 1024 + head * 64 + nt * 16 + l16] = f2bf(accA[nt][r] * inv);
    }
    int qb2 = qa + 16;
    if (qb2 < S_) {
      float inv = 1.f / psB[r];
#pragma unroll
      for (int nt = 0; nt < 4; ++nt)
        ao[((size_t)b * S_ + qb2) * 1024 + head * 64 + nt * 16 + l16] = f2bf(accB[nt][r] * inv);
    }
  }
}

extern "C" void kernel_launch(void* const* d_in, const int* in_sizes, int n_in,
                              void* d_out, int out_size, void* d_ws, size_t ws_size,
                              hipStream_t stream) {
  const float* query = (const float*)d_in[0];
  const float* key   = (const float*)d_in[1];
  const float* value = (const float*)d_in[2];
  const float* Wq    = (const float*)d_in[3];
  const float* Wk    = (const float*)d_in[4];
  const float* Wv    = (const float*)d_in[5];
  const float* Wo    = (const float*)d_in[6];
  const float* rel   = (const float*)d_in[7];

  char* ws = (char*)d_ws;
  size_t off = 0;
  auto alloc = [&](size_t bytes) { char* p = ws + off; off += (bytes + 255) & ~(size_t)255; return p; };

  const size_t MEelems = (size_t)M_ * E_;             // 15,859,712
  ushort* wqT = (ushort*)alloc((size_t)1024 * 1024 * 2);
  ushort* wkT = (ushort*)alloc((size_t)256 * 1024 * 2);   // contiguous with wvT:
  ushort* wvT = (ushort*)alloc((size_t)256 * 1024 * 2);   // [wkT; wvT] = 512x1024 B matrix
  ushort* woT = (ushort*)alloc((size_t)1024 * 1024 * 2);
  ushort* qp  = (ushort*)alloc((size_t)B_ * NH * SP * 64 * 2);   // 32 MB
  ushort* kp  = (ushort*)alloc((size_t)B_ * 4 * SP * 64 * 2);    // 8 MB
  ushort* vp  = (ushort*)alloc((size_t)B_ * 4 * 64 * SP * 2);    // 8 MB
  ushort* ao  = (ushort*)alloc(MEelems * 2);
  (void)wvT;

  transpose_all<<<2560, 256, 0, stream>>>(Wq, Wk, Wv, Wo, wqT, wkT, wvT, woT);

  const float QSCALE = 0.125f * 1.44269504f;   // fold 1/sqrt(D) and log2e into q
  qproj256<<<488, 512, 0, stream>>>(query, wqT, qp, QSCALE);
  kvproj256<<<244, 512, 0, stream>>>(key, value, wkT, kp, vp);

  attn_kernel<<<2048, 256, 0, stream>>>(qp, kp, vp, rel, ao);

  gemm_cnt256<2><<<244, 512, 0, stream>>>(ao, woT, d_out, 1.0f);
}

// Round 17
// 257.756 us; speedup vs baseline: 1.0752x; 1.0752x over previous
//
#include <hip/hip_runtime.h>
#include <hip/hip_bf16.h>

typedef __attribute__((ext_vector_type(8))) short short8;
typedef __attribute__((ext_vector_type(4))) float f32x4;
typedef __attribute__((ext_vector_type(4))) unsigned uintx4;

#define B_  32
#define S_  484
#define E_  1024
#define NH  16
#define SP  512          // padded sequence length
#define M_  (B_*S_)      // 15488

static __device__ __forceinline__ ushort f2bf(float f) {
  union { float f; unsigned u; } v; v.f = f;
  unsigned u = v.u;
  return (ushort)((u + 0x7FFFu + ((u >> 16) & 1u)) >> 16);
}

static __device__ __forceinline__ unsigned cvt_pk_bf16(float lo, float hi) {
  unsigned r;
  asm("v_cvt_pk_bf16_f32 %0, %1, %2" : "=v"(r) : "v"(lo), "v"(hi));
  return r;
}

#define GLOAD_LDS16(gp, lp) \
  __builtin_amdgcn_global_load_lds((const __attribute__((address_space(1))) void*)(gp), \
                                   (__attribute__((address_space(3))) void*)(lp), 16, 0, 0)

// ---------------- prep: 4 weight transposes + query f32->bf16, one launch ----------------
// blocks 0..2559: transpose tiles; blocks 2560..4607: grid-stride cvt of query.
__global__ __launch_bounds__(256)
void prep_all(const float* __restrict__ Wq, const float* __restrict__ Wk,
              const float* __restrict__ Wv, const float* __restrict__ Wo,
              ushort* __restrict__ wqT, ushort* __restrict__ wkT,
              ushort* __restrict__ wvT, ushort* __restrict__ woT,
              const float* __restrict__ query, ushort* __restrict__ qb, int n4) {
  if (blockIdx.x >= 2560) {
    int i = (blockIdx.x - 2560) * 256 + threadIdx.x;
    int stride = 2048 * 256;
    for (; i < n4; i += stride) {
      float4 v = ((const float4*)query)[i];
      ushort4 h;
      h.x = f2bf(v.x); h.y = f2bf(v.y); h.z = f2bf(v.z); h.w = f2bf(v.w);
      ((ushort4*)qb)[i] = h;
    }
    return;
  }
  __shared__ float tile[32][33];
  int t = blockIdx.x;
  const float* W; ushort* WT; int N;
  if (t < 1024)      { W = Wq; WT = wqT; N = 1024; }
  else if (t < 1280) { W = Wk; WT = wkT; N = 256;  t -= 1024; }
  else if (t < 1536) { W = Wv; WT = wvT; N = 256;  t -= 1280; }
  else               { W = Wo; WT = woT; N = 1024; t -= 1536; }
  const int nx = N >> 5;
  const int n0 = (t % nx) * 32, k0 = (t / nx) * 32;
  const int tx = threadIdx.x & 31, ty = threadIdx.x >> 5;   // 32 x 8
  for (int i = ty; i < 32; i += 8) tile[i][tx] = W[(size_t)(k0 + i) * N + n0 + tx];
  __syncthreads();
  for (int i = ty; i < 32; i += 8) WT[(size_t)(n0 + i) * 1024 + k0 + tx] = f2bf(tile[tx][i]);
}

// ======== counted-vmcnt GEMM: 256x256 tile, 512 thr, 4-buffer depth-3 ========
// EPI 0: bf16 out (scaled), ((b*NH+h)*SP + pos)*64 + (n&63)    (qp)
// EPI 2: f32 out, row-major [M][1024]                          (d_out)
template<int EPI>
__global__ __launch_bounds__(512)
void gemm_cnt256(const ushort* __restrict__ A, const ushort* __restrict__ BT,
                 void* __restrict__ Cout, float oscale) {
  const int K = 1024, N = 1024, NK = 32;
  __shared__ alignas(16) ushort sA[4][256 * 32];
  __shared__ alignas(16) ushort sB[4][256 * 32];
  const int tid = threadIdx.x;
  const int lane = tid & 63, w = tid >> 6;        // 8 waves

  const int nwg = gridDim.x;
  const int qq = nwg >> 3, rr = nwg & 7;
  const int x = blockIdx.x & 7, seq = blockIdx.x >> 3;
  const int logical = x * qq + (x < rr ? x : rr) + seq;
  const int m0 = (logical >> 2) * 256;            // 61 m-tiles
  const int n0 = (logical & 3) * 256;             // 4 n-tiles

  const int brow = tid >> 2;
  const int scol = (((tid & 3) ^ ((tid >> 3) & 3))) * 8;
  const int rowA0 = min(m0 + brow, M_ - 1);
  const int rowA1 = min(m0 + brow + 128, M_ - 1);
  const ushort* gA0 = A + (size_t)rowA0 * K + scol;
  const ushort* gA1 = A + (size_t)rowA1 * K + scol;
  const ushort* gB0 = BT + (size_t)(n0 + brow) * K + scol;
  const int dst = tid * 8;

  const int wr = w >> 2, wc = w & 3;              // 2x4 wave grid, each 128x64
  const int g4 = lane >> 4, l16 = lane & 15;
  const int rs = (l16 >> 1) & 3;

  f32x4 acc[8][4] = {};

  auto stage = [&](int kt, int buf) {
    GLOAD_LDS16(gA0 + kt * 32,           &sA[buf][dst]);
    GLOAD_LDS16(gA1 + kt * 32,           &sA[buf][dst + 4096]);
    GLOAD_LDS16(gB0 + kt * 32,           &sB[buf][dst]);
    GLOAD_LDS16(gB0 + kt * 32 + 128 * K, &sB[buf][dst + 4096]);
  };

  stage(0, 0);
  stage(1, 1);
  stage(2, 2);

  int cur = 0;
  for (int kt = 0; kt < NK; ++kt) {
    if (kt < NK - 2)       asm volatile("s_waitcnt vmcnt(8)" ::: "memory");
    else if (kt == NK - 2) asm volatile("s_waitcnt vmcnt(4)" ::: "memory");
    else                   asm volatile("s_waitcnt vmcnt(0)" ::: "memory");
    asm volatile("s_waitcnt lgkmcnt(0)" ::: "memory");
    __builtin_amdgcn_s_barrier();
    if (kt + 3 < NK) stage(kt + 3, (cur + 3) & 3);
    const ushort* pa = &sA[cur][(wr * 128 + l16) * 32 + 8 * (g4 ^ rs)];
    const ushort* pb = &sB[cur][(wc * 64 + l16) * 32 + 8 * (g4 ^ rs)];
    short8 af[8], bf[4];
#pragma unroll
    for (int i = 0; i < 8; ++i) af[i] = *(const short8*)(pa + i * 16 * 32);
#pragma unroll
    for (int i = 0; i < 4; ++i) bf[i] = *(const short8*)(pb + i * 16 * 32);
#pragma unroll
    for (int mi = 0; mi < 8; ++mi)
#pragma unroll
      for (int ni = 0; ni < 4; ++ni)
        acc[mi][ni] = __builtin_amdgcn_mfma_f32_16x16x32_bf16(af[mi], bf[ni], acc[mi][ni], 0, 0, 0);
    cur = (cur + 1) & 3;
  }

#pragma unroll
  for (int mi = 0; mi < 8; ++mi) {
#pragma unroll
    for (int ni = 0; ni < 4; ++ni) {
#pragma unroll
      for (int r = 0; r < 4; ++r) {
        int m = m0 + wr * 128 + mi * 16 + g4 * 4 + r;
        int n = n0 + wc * 64 + ni * 16 + l16;
        if (m < M_) {
          float vv = acc[mi][ni][r];
          if (EPI == 2) {
            ((float*)Cout)[(size_t)m * N + n] = vv;
          } else {
            int b = m / S_, pos = m % S_;
            ushort hv = f2bf(vv * oscale);
            ((ushort*)Cout)[(((size_t)b * NH + (n >> 6)) * SP + pos) * 64 + (n & 63)] = hv;
          }
        }
      }
    }
  }
}

// ======== K+V projections: 256m x 128n tiles, counted-vmcnt depth-3, f32-A ========
// (R14-proven version, exact)
__global__ __launch_bounds__(512, 2)
void kvproj256(const float* __restrict__ key, const float* __restrict__ value,
               const ushort* __restrict__ BT,
               ushort* __restrict__ kp, ushort* __restrict__ vp) {
  const int K = 1024, NK = 32;
  __shared__ alignas(16) ushort sA[4][256 * 32];   // 64 KB
  __shared__ alignas(16) ushort sB[4][128 * 32];   // 32 KB
  const int tid = threadIdx.x;
  const int lane = tid & 63, w = tid >> 6;         // 8 waves

  const int nwg = gridDim.x;                       // 244: qq=30, rr=4
  const int qq = nwg >> 3, rr = nwg & 7;
  const int x = blockIdx.x & 7, seq = blockIdx.x >> 3;
  const int logical = x * qq + (x < rr ? x : rr) + seq;
  const int m0 = (logical >> 2) * 256;             // 61 m-tiles
  const int sub = logical & 3;
  const bool isV = sub >= 2;
  const int n0l = (sub & 1) * 128;
  const float* Ain = isV ? value : key;

  const int brow = tid >> 2;
  const int scol = (((tid & 3) ^ ((tid >> 3) & 3))) * 8;
  const ushort* gB0 = BT + (size_t)((isV ? 256 : 0) + n0l + brow) * K + scol;
  const int dstB = tid * 8;

  const int arow = tid >> 1;
  const int rowAf = min(m0 + arow, M_ - 1);
  const float* gAf = Ain + (size_t)rowAf * K + (tid & 1) * 16;
  const int sw = (arow >> 1) & 3;
  const int ag0 = (2 * (tid & 1)) ^ sw;
  const int ag1 = (2 * (tid & 1) + 1) ^ sw;

  const int wr = w >> 1, wc = w & 1;               // 4x2 wave grid, each 64x64
  const int g4 = lane >> 4, l16 = lane & 15;
  const int rs = (l16 >> 1) & 3;

  f32x4 acc[4][4] = {};
  float4 fA[3][4];

  auto stageB = [&](int kt) {
    GLOAD_LDS16(gB0 + kt * 32, &sB[kt & 3][dstB]);
  };
  auto compute = [&](int kt) {
    const int buf = kt & 3;
    const ushort* pa = &sA[buf][(wr * 64 + l16) * 32 + 8 * (g4 ^ rs)];
    const ushort* pb = &sB[buf][(wc * 64 + l16) * 32 + 8 * (g4 ^ rs)];
    short8 af[4], bf[4];
#pragma unroll
    for (int i = 0; i < 4; ++i) {
      af[i] = *(const short8*)(pa + i * 16 * 32);
      bf[i] = *(const short8*)(pb + i * 16 * 32);
    }
#pragma unroll
    for (int mi = 0; mi < 4; ++mi)
#pragma unroll
      for (int ni = 0; ni < 4; ++ni)
        acc[mi][ni] = __builtin_amdgcn_mfma_f32_16x16x32_bf16(af[mi], bf[ni], acc[mi][ni], 0, 0, 0);
  };

#define ISSUEA(kt, slot) do { \
    const float4* _p = (const float4*)(gAf + (kt) * 32); \
    fA[slot][0] = _p[0]; fA[slot][1] = _p[1]; fA[slot][2] = _p[2]; fA[slot][3] = _p[3]; \
  } while (0)
#define WRITEA(kt, slot) do { \
    unsigned _d0 = cvt_pk_bf16(fA[slot][0].x, fA[slot][0].y), _d1 = cvt_pk_bf16(fA[slot][0].z, fA[slot][0].w); \
    unsigned _d2 = cvt_pk_bf16(fA[slot][1].x, fA[slot][1].y), _d3 = cvt_pk_bf16(fA[slot][1].z, fA[slot][1].w); \
    unsigned _d4 = cvt_pk_bf16(fA[slot][2].x, fA[slot][2].y), _d5 = cvt_pk_bf16(fA[slot][2].z, fA[slot][2].w); \
    unsigned _d6 = cvt_pk_bf16(fA[slot][3].x, fA[slot][3].y), _d7 = cvt_pk_bf16(fA[slot][3].z, fA[slot][3].w); \
    ushort* _base = &sA[(kt) & 3][arow * 32]; \
    uintx4 _q0 = {_d0, _d1, _d2, _d3}, _q1 = {_d4, _d5, _d6, _d7}; \
    *(uintx4*)(_base + ag0 * 8) = _q0; \
    *(uintx4*)(_base + ag1 * 8) = _q1; \
  } while (0)
#define KSTEP(kt, ws, is) do { \
    if ((kt) < NK - 2) asm volatile("s_waitcnt vmcnt(5)" ::: "memory"); \
    else               asm volatile("s_waitcnt vmcnt(0)" ::: "memory"); \
    if ((kt) + 1 < NK) WRITEA((kt) + 1, ws); \
    asm volatile("s_waitcnt lgkmcnt(0)" ::: "memory"); \
    __builtin_amdgcn_s_barrier(); \
    if ((kt) + 3 < NK) { stageB((kt) + 3); ISSUEA((kt) + 3, is); } \
    compute(kt); \
  } while (0)

  stageB(0); ISSUEA(0, 0);
  stageB(1); ISSUEA(1, 1);
  stageB(2); ISSUEA(2, 2);
  asm volatile("s_waitcnt vmcnt(10)" ::: "memory");
  WRITEA(0, 0);

  for (int kb = 0; kb < 30; kb += 3) {
    KSTEP(kb,     1, 0);
    KSTEP(kb + 1, 2, 1);
    KSTEP(kb + 2, 0, 2);
  }
  KSTEP(30, 1, 0);
  KSTEP(31, 0, 0);

#undef KSTEP
#undef WRITEA
#undef ISSUEA

#pragma unroll
  for (int mi = 0; mi < 4; ++mi) {
#pragma unroll
    for (int ni = 0; ni < 4; ++ni) {
#pragma unroll
      for (int r = 0; r < 4; ++r) {
        int m = m0 + wr * 64 + mi * 16 + g4 * 4 + r;
        int nl = n0l + wc * 64 + ni * 16 + l16;
        if (m < M_) {
          float vv = acc[mi][ni][r];
          int b = m / S_, pos = m % S_;
          int h = nl >> 6, d = nl & 63;
          if (!isV) {
            int dd = d ^ ((pos & 7) << 3);           // K-LDS row bank swizzle
            kp[(((size_t)b * 4 + h) * SP + pos) * 64 + dd] = f2bf(vv);
          } else {
            int local = pos & 31;                    // sigma permute + granule xor
            int j = (local < 16) ? (2 * local) : (2 * local - 31);
            int pf_ = (pos & ~31) | (j ^ ((d & 3) << 3));
            vp[(((size_t)b * 4 + h) * 64 + d) * SP + pf_] = f2bf(vv);
          }
        }
      }
    }
  }
}

// ---------------- fused GQA attention: 32 q-rows per wave, shared K/V frags ----------------
// (R14-proven version, exact)
__global__ __launch_bounds__(256)
void attn_kernel(const ushort* __restrict__ qp, const ushort* __restrict__ kp,
                 const ushort* __restrict__ vpT, const float* __restrict__ rel,
                 ushort* __restrict__ ao) {
  __shared__ float2 sBiasP[1056];                 // (b[i], b[i+16]) pairs, +32 guard
  __shared__ alignas(16) ushort sK[2][32 * 64];
  __shared__ alignas(16) ushort sV[2][64 * 32];
  __shared__ alignas(16) ushort sP[4][32 * 40];
  const int tid = threadIdx.x;
  const int blk = blockIdx.x;
  const int logical = (blk & 7) * 256 + (blk >> 3);     // bijective (2048 = 8*256)
  const int qt = logical & 3, head = (logical >> 2) & 15, b = logical >> 6;
  const int g = head >> 2;
  const float LOG2E = 1.44269504f;
  for (int t = tid; t < 1056; t += 256) {
    float b0 = (t >= 32 && t < 999) ? rel[(t - 32) * 16 + head] * LOG2E : -1e30f;
    int t2 = t + 16;
    float b1 = (t2 >= 32 && t2 < 999) ? rel[(t2 - 32) * 16 + head] * LOG2E : -1e30f;
    sBiasP[t] = make_float2(b0, b1);
  }

  const int lane = tid & 63, w = tid >> 6;
  const int g4 = lane >> 4, l16 = lane & 15;
  const int qw = qt * 128 + w * 32;

  const ushort* qbA = qp + (((size_t)b * NH + head) * SP + qw + l16) * 64;
  const ushort* qbB = qbA + 16 * 64;
  short8 qf0a = *(const short8*)(qbA + 8 * g4);
  short8 qf1a = *(const short8*)(qbA + 32 + 8 * g4);
  short8 qf0b = *(const short8*)(qbB + 8 * g4);
  short8 qf1b = *(const short8*)(qbB + 32 + 8 * g4);

  const ushort* kSrc = kp  + ((size_t)b * 4 + g) * SP * 64 + (tid >> 3) * 64 + (tid & 7) * 8;
  const ushort* vSrc = vpT + ((size_t)b * 4 + g) * 64 * SP + (tid >> 2) * SP + (tid & 3) * 8;

  f32x4 accA[4] = {}, accB[4] = {};
  float psA[4] = {0.f, 0.f, 0.f, 0.f}, psB[4] = {0.f, 0.f, 0.f, 0.f};
  const int ibA = l16 - (qw + g4 * 4) + 515;      // pair-table idx (guard +32)
  const int ibB = ibA - 16;
  ushort* sPw = &sP[w][0];

  const int kswz  = (l16 & 7) << 3;
  const int kOff0 = l16 * 64 + ((8 * g4) ^ kswz);
  const int kOff1 = l16 * 64 + ((32 + 8 * g4) ^ kswz);
  const int vOff  = l16 * 32 + 8 * (g4 ^ (l16 & 3));

  GLOAD_LDS16(kSrc, &sK[0][w * 512]);
  GLOAD_LDS16(vSrc, &sV[0][w * 512]);

  for (int kt = 0; kt < 16; ++kt) {
    __syncthreads();
    if (kt + 1 < 16) {
      GLOAD_LDS16(kSrc + (kt + 1) * 2048, &sK[(kt + 1) & 1][w * 512]);
      GLOAD_LDS16(vSrc + (kt + 1) * 32,   &sV[(kt + 1) & 1][w * 512]);
    }
    const int k0 = kt * 32;
    float2 a0 = sBiasP[ibA + k0],     a1 = sBiasP[ibA + k0 - 1];
    float2 a2 = sBiasP[ibA + k0 - 2], a3 = sBiasP[ibA + k0 - 3];
    float2 c0 = sBiasP[ibB + k0],     c1 = sBiasP[ibB + k0 - 1];
    float2 c2 = sBiasP[ibB + k0 - 2], c3 = sBiasP[ibB + k0 - 3];
    f32x4 s0a = {a0.x, a1.x, a2.x, a3.x}, s1a = {a0.y, a1.y, a2.y, a3.y};
    f32x4 s0b = {c0.x, c1.x, c2.x, c3.x}, s1b = {c0.y, c1.y, c2.y, c3.y};

    const ushort* sk = &sK[kt & 1][0];
    const ushort* sv = &sV[kt & 1][0];
    short8 kf0 = *(const short8*)(sk + kOff0);
    short8 kf1 = *(const short8*)(sk + kOff1);
    short8 kf2 = *(const short8*)(sk + 1024 + kOff0);
    short8 kf3 = *(const short8*)(sk + 1024 + kOff1);
    s0a = __builtin_amdgcn_mfma_f32_16x16x32_bf16(qf0a, kf0, s0a, 0, 0, 0);
    s0a = __builtin_amdgcn_mfma_f32_16x16x32_bf16(qf1a, kf1, s0a, 0, 0, 0);
    s1a = __builtin_amdgcn_mfma_f32_16x16x32_bf16(qf0a, kf2, s1a, 0, 0, 0);
    s1a = __builtin_amdgcn_mfma_f32_16x16x32_bf16(qf1a, kf3, s1a, 0, 0, 0);
    s0b = __builtin_amdgcn_mfma_f32_16x16x32_bf16(qf0b, kf0, s0b, 0, 0, 0);
    s0b = __builtin_amdgcn_mfma_f32_16x16x32_bf16(qf1b, kf1, s0b, 0, 0, 0);
    s1b = __builtin_amdgcn_mfma_f32_16x16x32_bf16(qf0b, kf2, s1b, 0, 0, 0);
    s1b = __builtin_amdgcn_mfma_f32_16x16x32_bf16(qf1b, kf3, s1b, 0, 0, 0);

#pragma unroll
    for (int r = 0; r < 4; ++r) {
      float p0 = __builtin_amdgcn_exp2f(s0a[r]);
      float p1 = __builtin_amdgcn_exp2f(s1a[r]);
      float u0 = __builtin_amdgcn_exp2f(s0b[r]);
      float u1 = __builtin_amdgcn_exp2f(s1b[r]);
      if (kt == 15) {
        bool m0v = (k0 + l16 < S_), m1v = (k0 + 16 + l16 < S_);
        p0 = m0v ? p0 : 0.f;  p1 = m1v ? p1 : 0.f;
        u0 = m0v ? u0 : 0.f;  u1 = m1v ? u1 : 0.f;
      }
      psA[r] += p0 + p1;
      psB[r] += u0 + u1;
      *(unsigned*)(sPw + (g4 * 4 + r) * 40 + 2 * l16)        = cvt_pk_bf16(p0, p1);
      *(unsigned*)(sPw + (16 + g4 * 4 + r) * 40 + 2 * l16)   = cvt_pk_bf16(u0, u1);
    }
    short8 pfA = *(const short8*)(sPw + l16 * 40 + 8 * g4);
    short8 pfB = *(const short8*)(sPw + (16 + l16) * 40 + 8 * g4);
#pragma unroll
    for (int nt = 0; nt < 4; ++nt) {
      short8 vf = *(const short8*)(sv + vOff + nt * 512);    // shared by both sub-tiles
      accA[nt] = __builtin_amdgcn_mfma_f32_16x16x32_bf16(pfA, vf, accA[nt], 0, 0, 0);
      accB[nt] = __builtin_amdgcn_mfma_f32_16x16x32_bf16(pfB, vf, accB[nt], 0, 0, 0);
    }
  }

#pragma unroll
  for (int off = 1; off < 16; off <<= 1) {
#pragma unroll
    for (int r = 0; r < 4; ++r) {
      psA[r] += __shfl_xor(psA[r], off, 64);
      psB[r] += __shfl_xor(psB[r], off, 64);
    }
  }

#pragma unroll
  for (int r = 0; r < 4; ++r) {
    int qa = qw + g4 * 4 + r;
    if (qa < S_) {
      float inv = 1.f / psA[r];
#pragma unroll
      for (int nt = 0; nt < 4; ++nt)
        ao[((size_t)b * S_ + qa) * 1024 + head * 64 + nt * 16 + l16] = f2bf(accA[nt][r] * inv);
    }
    int qb2 = qa + 16;
    if (qb2 < S_) {
      float inv = 1.f / psB[r];
#pragma unroll
      for (int nt = 0; nt < 4; ++nt)
        ao[((size_t)b * S_ + qb2) * 1024 + head * 64 + nt * 16 + l16] = f2bf(accB[nt][r] * inv);
    }
  }
}

extern "C" void kernel_launch(void* const* d_in, const int* in_sizes, int n_in,
                              void* d_out, int out_size, void* d_ws, size_t ws_size,
                              hipStream_t stream) {
  const float* query = (const float*)d_in[0];
  const float* key   = (const float*)d_in[1];
  const float* value = (const float*)d_in[2];
  const float* Wq    = (const float*)d_in[3];
  const float* Wk    = (const float*)d_in[4];
  const float* Wv    = (const float*)d_in[5];
  const float* Wo    = (const float*)d_in[6];
  const float* rel   = (const float*)d_in[7];

  char* ws = (char*)d_ws;
  size_t off = 0;
  auto alloc = [&](size_t bytes) { char* p = ws + off; off += (bytes + 255) & ~(size_t)255; return p; };

  const size_t MEelems = (size_t)M_ * E_;             // 15,859,712
  ushort* qb  = (ushort*)alloc(MEelems * 2);          // query in bf16
  ushort* wqT = (ushort*)alloc((size_t)1024 * 1024 * 2);
  ushort* wkT = (ushort*)alloc((size_t)256 * 1024 * 2);   // contiguous with wvT:
  ushort* wvT = (ushort*)alloc((size_t)256 * 1024 * 2);   // [wkT; wvT] = 512x1024 B matrix
  ushort* woT = (ushort*)alloc((size_t)1024 * 1024 * 2);
  ushort* qp  = (ushort*)alloc((size_t)B_ * NH * SP * 64 * 2);   // 32 MB
  ushort* kp  = (ushort*)alloc((size_t)B_ * 4 * SP * 64 * 2);    // 8 MB
  ushort* vp  = (ushort*)alloc((size_t)B_ * 4 * 64 * SP * 2);    // 8 MB
  ushort* ao  = (ushort*)alloc(MEelems * 2);
  (void)wvT;

  prep_all<<<4608, 256, 0, stream>>>(Wq, Wk, Wv, Wo, wqT, wkT, wvT, woT,
                                     query, qb, (int)(MEelems / 4));

  const float QSCALE = 0.125f * 1.44269504f;   // fold 1/sqrt(D) and log2e into q
  gemm_cnt256<0><<<244, 512, 0, stream>>>(qb, wqT, qp, QSCALE);
  kvproj256<<<244, 512, 0, stream>>>(key, value, wkT, kp, vp);

  attn_kernel<<<2048, 256, 0, stream>>>(qp, kp, vp, rel, ao);

  gemm_cnt256<2><<<244, 512, 0, stream>>>(ao, woT, d_out, 1.0f);
}

// Round 18
// 253.429 us; speedup vs baseline: 1.0935x; 1.0171x over previous
//
#include <hip/hip_runtime.h>
#include <hip/hip_bf16.h>

typedef __attribute__((ext_vector_type(8))) short short8;
typedef __attribute__((ext_vector_type(4))) float f32x4;
typedef __attribute__((ext_vector_type(4))) unsigned uintx4;

#define B_  32
#define S_  484
#define E_  1024
#define NH  16
#define SP  512          // padded sequence length
#define M_  (B_*S_)      // 15488

static __device__ __forceinline__ ushort f2bf(float f) {
  union { float f; unsigned u; } v; v.f = f;
  unsigned u = v.u;
  return (ushort)((u + 0x7FFFu + ((u >> 16) & 1u)) >> 16);
}

static __device__ __forceinline__ unsigned cvt_pk_bf16(float lo, float hi) {
  unsigned r;
  asm("v_cvt_pk_bf16_f32 %0, %1, %2" : "=v"(r) : "v"(lo), "v"(hi));
  return r;
}

#define GLOAD_LDS16(gp, lp) \
  __builtin_amdgcn_global_load_lds((const __attribute__((address_space(1))) void*)(gp), \
                                   (__attribute__((address_space(3))) void*)(lp), 16, 0, 0)

// ---------------- prep: 4 weight transposes + query f32->bf16, one launch ----------------
__global__ __launch_bounds__(256)
void prep_all(const float* __restrict__ Wq, const float* __restrict__ Wk,
              const float* __restrict__ Wv, const float* __restrict__ Wo,
              ushort* __restrict__ wqT, ushort* __restrict__ wkT,
              ushort* __restrict__ wvT, ushort* __restrict__ woT,
              const float* __restrict__ query, ushort* __restrict__ qb, int n4) {
  if (blockIdx.x >= 2560) {
    int i = (blockIdx.x - 2560) * 256 + threadIdx.x;
    int stride = 2048 * 256;
    for (; i < n4; i += stride) {
      float4 v = ((const float4*)query)[i];
      ushort4 h;
      h.x = f2bf(v.x); h.y = f2bf(v.y); h.z = f2bf(v.z); h.w = f2bf(v.w);
      ((ushort4*)qb)[i] = h;
    }
    return;
  }
  __shared__ float tile[32][33];
  int t = blockIdx.x;
  const float* W; ushort* WT; int N;
  if (t < 1024)      { W = Wq; WT = wqT; N = 1024; }
  else if (t < 1280) { W = Wk; WT = wkT; N = 256;  t -= 1024; }
  else if (t < 1536) { W = Wv; WT = wvT; N = 256;  t -= 1280; }
  else               { W = Wo; WT = woT; N = 1024; t -= 1536; }
  const int nx = N >> 5;
  const int n0 = (t % nx) * 32, k0 = (t / nx) * 32;
  const int tx = threadIdx.x & 31, ty = threadIdx.x >> 5;   // 32 x 8
  for (int i = ty; i < 32; i += 8) tile[i][tx] = W[(size_t)(k0 + i) * N + n0 + tx];
  __syncthreads();
  for (int i = ty; i < 32; i += 8) WT[(size_t)(n0 + i) * 1024 + k0 + tx] = f2bf(tile[tx][i]);
}

// ======== counted-vmcnt GEMM: 256x256 tile, 512 thr, 4-buffer depth-3 ========
// EPI 0: bf16 out (scaled), ((b*NH+h)*SP + pos)*64 + (n&63)    (qp)
// EPI 2: f32 out, row-major [M][1024]                          (d_out)
template<int EPI>
__global__ __launch_bounds__(512)
void gemm_cnt256(const ushort* __restrict__ A, const ushort* __restrict__ BT,
                 void* __restrict__ Cout, float oscale) {
  const int K = 1024, N = 1024, NK = 32;
  __shared__ alignas(16) ushort sA[4][256 * 32];
  __shared__ alignas(16) ushort sB[4][256 * 32];
  const int tid = threadIdx.x;
  const int lane = tid & 63, w = tid >> 6;        // 8 waves

  const int nwg = gridDim.x;
  const int qq = nwg >> 3, rr = nwg & 7;
  const int x = blockIdx.x & 7, seq = blockIdx.x >> 3;
  const int logical = x * qq + (x < rr ? x : rr) + seq;
  const int m0 = (logical >> 2) * 256;            // 61 m-tiles
  const int n0 = (logical & 3) * 256;             // 4 n-tiles

  const int brow = tid >> 2;
  const int scol = (((tid & 3) ^ ((tid >> 3) & 3))) * 8;
  const int rowA0 = min(m0 + brow, M_ - 1);
  const int rowA1 = min(m0 + brow + 128, M_ - 1);
  const ushort* gA0 = A + (size_t)rowA0 * K + scol;
  const ushort* gA1 = A + (size_t)rowA1 * K + scol;
  const ushort* gB0 = BT + (size_t)(n0 + brow) * K + scol;
  const int dst = tid * 8;

  const int wr = w >> 2, wc = w & 3;              // 2x4 wave grid, each 128x64
  const int g4 = lane >> 4, l16 = lane & 15;
  const int rs = (l16 >> 1) & 3;

  f32x4 acc[8][4] = {};

  auto stage = [&](int kt, int buf) {
    GLOAD_LDS16(gA0 + kt * 32,           &sA[buf][dst]);
    GLOAD_LDS16(gA1 + kt * 32,           &sA[buf][dst + 4096]);
    GLOAD_LDS16(gB0 + kt * 32,           &sB[buf][dst]);
    GLOAD_LDS16(gB0 + kt * 32 + 128 * K, &sB[buf][dst + 4096]);
  };

  stage(0, 0);
  stage(1, 1);
  stage(2, 2);

  int cur = 0;
  for (int kt = 0; kt < NK; ++kt) {
    if (kt < NK - 2)       asm volatile("s_waitcnt vmcnt(8)" ::: "memory");
    else if (kt == NK - 2) asm volatile("s_waitcnt vmcnt(4)" ::: "memory");
    else                   asm volatile("s_waitcnt vmcnt(0)" ::: "memory");
    asm volatile("s_waitcnt lgkmcnt(0)" ::: "memory");
    __builtin_amdgcn_s_barrier();
    if (kt + 3 < NK) stage(kt + 3, (cur + 3) & 3);
    const ushort* pa = &sA[cur][(wr * 128 + l16) * 32 + 8 * (g4 ^ rs)];
    const ushort* pb = &sB[cur][(wc * 64 + l16) * 32 + 8 * (g4 ^ rs)];
    short8 af[8], bf[4];
#pragma unroll
    for (int i = 0; i < 8; ++i) af[i] = *(const short8*)(pa + i * 16 * 32);
#pragma unroll
    for (int i = 0; i < 4; ++i) bf[i] = *(const short8*)(pb + i * 16 * 32);
#pragma unroll
    for (int mi = 0; mi < 8; ++mi)
#pragma unroll
      for (int ni = 0; ni < 4; ++ni)
        acc[mi][ni] = __builtin_amdgcn_mfma_f32_16x16x32_bf16(af[mi], bf[ni], acc[mi][ni], 0, 0, 0);
    cur = (cur + 1) & 3;
  }

#pragma unroll
  for (int mi = 0; mi < 8; ++mi) {
#pragma unroll
    for (int ni = 0; ni < 4; ++ni) {
#pragma unroll
      for (int r = 0; r < 4; ++r) {
        int m = m0 + wr * 128 + mi * 16 + g4 * 4 + r;
        int n = n0 + wc * 64 + ni * 16 + l16;
        if (m < M_) {
          float vv = acc[mi][ni][r];
          if (EPI == 2) {
            ((float*)Cout)[(size_t)m * N + n] = vv;
          } else {
            int b = m / S_, pos = m % S_;
            ushort hv = f2bf(vv * oscale);
            ((ushort*)Cout)[(((size_t)b * NH + (n >> 6)) * SP + pos) * 64 + (n & 63)] = hv;
          }
        }
      }
    }
  }
}

// ======== K+V projections: 256m x 128n tiles, counted-vmcnt depth-3, f32-A ========
// (R14-proven version, exact)
__global__ __launch_bounds__(512, 2)
void kvproj256(const float* __restrict__ key, const float* __restrict__ value,
               const ushort* __restrict__ BT,
               ushort* __restrict__ kp, ushort* __restrict__ vp) {
  const int K = 1024, NK = 32;
  __shared__ alignas(16) ushort sA[4][256 * 32];   // 64 KB
  __shared__ alignas(16) ushort sB[4][128 * 32];   // 32 KB
  const int tid = threadIdx.x;
  const int lane = tid & 63, w = tid >> 6;         // 8 waves

  const int nwg = gridDim.x;                       // 244: qq=30, rr=4
  const int qq = nwg >> 3, rr = nwg & 7;
  const int x = blockIdx.x & 7, seq = blockIdx.x >> 3;
  const int logical = x * qq + (x < rr ? x : rr) + seq;
  const int m0 = (logical >> 2) * 256;             // 61 m-tiles
  const int sub = logical & 3;
  const bool isV = sub >= 2;
  const int n0l = (sub & 1) * 128;
  const float* Ain = isV ? value : key;

  const int brow = tid >> 2;
  const int scol = (((tid & 3) ^ ((tid >> 3) & 3))) * 8;
  const ushort* gB0 = BT + (size_t)((isV ? 256 : 0) + n0l + brow) * K + scol;
  const int dstB = tid * 8;

  const int arow = tid >> 1;
  const int rowAf = min(m0 + arow, M_ - 1);
  const float* gAf = Ain + (size_t)rowAf * K + (tid & 1) * 16;
  const int sw = (arow >> 1) & 3;
  const int ag0 = (2 * (tid & 1)) ^ sw;
  const int ag1 = (2 * (tid & 1) + 1) ^ sw;

  const int wr = w >> 1, wc = w & 1;               // 4x2 wave grid, each 64x64
  const int g4 = lane >> 4, l16 = lane & 15;
  const int rs = (l16 >> 1) & 3;

  f32x4 acc[4][4] = {};
  float4 fA[3][4];

  auto stageB = [&](int kt) {
    GLOAD_LDS16(gB0 + kt * 32, &sB[kt & 3][dstB]);
  };
  auto compute = [&](int kt) {
    const int buf = kt & 3;
    const ushort* pa = &sA[buf][(wr * 64 + l16) * 32 + 8 * (g4 ^ rs)];
    const ushort* pb = &sB[buf][(wc * 64 + l16) * 32 + 8 * (g4 ^ rs)];
    short8 af[4], bf[4];
#pragma unroll
    for (int i = 0; i < 4; ++i) {
      af[i] = *(const short8*)(pa + i * 16 * 32);
      bf[i] = *(const short8*)(pb + i * 16 * 32);
    }
#pragma unroll
    for (int mi = 0; mi < 4; ++mi)
#pragma unroll
      for (int ni = 0; ni < 4; ++ni)
        acc[mi][ni] = __builtin_amdgcn_mfma_f32_16x16x32_bf16(af[mi], bf[ni], acc[mi][ni], 0, 0, 0);
  };

#define ISSUEA(kt, slot) do { \
    const float4* _p = (const float4*)(gAf + (kt) * 32); \
    fA[slot][0] = _p[0]; fA[slot][1] = _p[1]; fA[slot][2] = _p[2]; fA[slot][3] = _p[3]; \
  } while (0)
#define WRITEA(kt, slot) do { \
    unsigned _d0 = cvt_pk_bf16(fA[slot][0].x, fA[slot][0].y), _d1 = cvt_pk_bf16(fA[slot][0].z, fA[slot][0].w); \
    unsigned _d2 = cvt_pk_bf16(fA[slot][1].x, fA[slot][1].y), _d3 = cvt_pk_bf16(fA[slot][1].z, fA[slot][1].w); \
    unsigned _d4 = cvt_pk_bf16(fA[slot][2].x, fA[slot][2].y), _d5 = cvt_pk_bf16(fA[slot][2].z, fA[slot][2].w); \
    unsigned _d6 = cvt_pk_bf16(fA[slot][3].x, fA[slot][3].y), _d7 = cvt_pk_bf16(fA[slot][3].z, fA[slot][3].w); \
    ushort* _base = &sA[(kt) & 3][arow * 32]; \
    uintx4 _q0 = {_d0, _d1, _d2, _d3}, _q1 = {_d4, _d5, _d6, _d7}; \
    *(uintx4*)(_base + ag0 * 8) = _q0; \
    *(uintx4*)(_base + ag1 * 8) = _q1; \
  } while (0)
#define KSTEP(kt, ws, is) do { \
    if ((kt) < NK - 2) asm volatile("s_waitcnt vmcnt(5)" ::: "memory"); \
    else               asm volatile("s_waitcnt vmcnt(0)" ::: "memory"); \
    if ((kt) + 1 < NK) WRITEA((kt) + 1, ws); \
    asm volatile("s_waitcnt lgkmcnt(0)" ::: "memory"); \
    __builtin_amdgcn_s_barrier(); \
    if ((kt) + 3 < NK) { stageB((kt) + 3); ISSUEA((kt) + 3, is); } \
    compute(kt); \
  } while (0)

  stageB(0); ISSUEA(0, 0);
  stageB(1); ISSUEA(1, 1);
  stageB(2); ISSUEA(2, 2);
  asm volatile("s_waitcnt vmcnt(10)" ::: "memory");
  WRITEA(0, 0);

  for (int kb = 0; kb < 30; kb += 3) {
    KSTEP(kb,     1, 0);
    KSTEP(kb + 1, 2, 1);
    KSTEP(kb + 2, 0, 2);
  }
  KSTEP(30, 1, 0);
  KSTEP(31, 0, 0);

#undef KSTEP
#undef WRITEA
#undef ISSUEA

#pragma unroll
  for (int mi = 0; mi < 4; ++mi) {
#pragma unroll
    for (int ni = 0; ni < 4; ++ni) {
#pragma unroll
      for (int r = 0; r < 4; ++r) {
        int m = m0 + wr * 64 + mi * 16 + g4 * 4 + r;
        int nl = n0l + wc * 64 + ni * 16 + l16;
        if (m < M_) {
          float vv = acc[mi][ni][r];
          int b = m / S_, pos = m % S_;
          int h = nl >> 6, d = nl & 63;
          if (!isV) {
            int dd = d ^ ((pos & 7) << 3);           // K-LDS row bank swizzle
            kp[(((size_t)b * 4 + h) * SP + pos) * 64 + dd] = f2bf(vv);
          } else {
            int local = pos & 31;                    // sigma permute + granule xor
            int j = (local < 16) ? (2 * local) : (2 * local - 31);
            int pf_ = (pos & ~31) | (j ^ ((d & 3) << 3));
            vp[(((size_t)b * 4 + h) * 64 + d) * SP + pf_] = f2bf(vv);
          }
        }
      }
    }
  }
}

// ---------------- fused GQA attention: 32 q-rows per wave, block-local bias table ----------------
// Bias pair-table shrunk to the provable per-block window [tbase+4, tbase+626]
// (tbase = 384 - qt*128); local idx = global - tbase, qt-terms cancel.
// LDS 35328 -> 31744 => 5 blocks/CU (was 4).
__global__ __launch_bounds__(256)
void attn_kernel(const ushort* __restrict__ qp, const ushort* __restrict__ kp,
                 const ushort* __restrict__ vpT, const float* __restrict__ rel,
                 ushort* __restrict__ ao) {
  __shared__ float2 sBiasP[640];                  // block-local (b[i], b[i+16]) pairs
  __shared__ alignas(16) ushort sK[2][32 * 64];
  __shared__ alignas(16) ushort sV[2][64 * 32];
  __shared__ alignas(16) ushort sP[4][32 * 40];
  const int tid = threadIdx.x;
  const int blk = blockIdx.x;
  const int logical = (blk & 7) * 256 + (blk >> 3);     // bijective (2048 = 8*256)
  const int qt = logical & 3, head = (logical >> 2) & 15, b = logical >> 6;
  const int g = head >> 2;
  const float LOG2E = 1.44269504f;
  const int tbase = 384 - qt * 128;
  for (int t = tid; t < 640; t += 256) {
    int gi0 = t + tbase - 32;
    int gi1 = t + tbase - 16;
    float b0 = (gi0 >= 0 && gi0 < 967) ? rel[gi0 * 16 + head] * LOG2E : -1e30f;
    float b1 = (gi1 >= 0 && gi1 < 967) ? rel[gi1 * 16 + head] * LOG2E : -1e30f;
    sBiasP[t] = make_float2(b0, b1);
  }

  const int lane = tid & 63, w = tid >> 6;
  const int g4 = lane >> 4, l16 = lane & 15;
  const int qw = qt * 128 + w * 32;

  const ushort* qbA = qp + (((size_t)b * NH + head) * SP + qw + l16) * 64;
  const ushort* qbB = qbA + 16 * 64;
  short8 qf0a = *(const short8*)(qbA + 8 * g4);
  short8 qf1a = *(const short8*)(qbA + 32 + 8 * g4);
  short8 qf0b = *(const short8*)(qbB + 8 * g4);
  short8 qf1b = *(const short8*)(qbB + 32 + 8 * g4);

  const ushort* kSrc = kp  + ((size_t)b * 4 + g) * SP * 64 + (tid >> 3) * 64 + (tid & 7) * 8;
  const ushort* vSrc = vpT + ((size_t)b * 4 + g) * 64 * SP + (tid >> 2) * SP + (tid & 3) * 8;

  f32x4 accA[4] = {}, accB[4] = {};
  float psA[4] = {0.f, 0.f, 0.f, 0.f}, psB[4] = {0.f, 0.f, 0.f, 0.f};
  const int ibA = l16 - (w * 32 + g4 * 4) + 131;  // local pair idx (== old - tbase)
  const int ibB = ibA - 16;
  ushort* sPw = &sP[w][0];

  const int kswz  = (l16 & 7) << 3;
  const int kOff0 = l16 * 64 + ((8 * g4) ^ kswz);
  const int kOff1 = l16 * 64 + ((32 + 8 * g4) ^ kswz);
  const int vOff  = l16 * 32 + 8 * (g4 ^ (l16 & 3));

  GLOAD_LDS16(kSrc, &sK[0][w * 512]);
  GLOAD_LDS16(vSrc, &sV[0][w * 512]);

  for (int kt = 0; kt < 16; ++kt) {
    __syncthreads();
    if (kt + 1 < 16) {
      GLOAD_LDS16(kSrc + (kt + 1) * 2048, &sK[(kt + 1) & 1][w * 512]);
      GLOAD_LDS16(vSrc + (kt + 1) * 32,   &sV[(kt + 1) & 1][w * 512]);
    }
    const int k0 = kt * 32;
    float2 a0 = sBiasP[ibA + k0],     a1 = sBiasP[ibA + k0 - 1];
    float2 a2 = sBiasP[ibA + k0 - 2], a3 = sBiasP[ibA + k0 - 3];
    float2 c0 = sBiasP[ibB + k0],     c1 = sBiasP[ibB + k0 - 1];
    float2 c2 = sBiasP[ibB + k0 - 2], c3 = sBiasP[ibB + k0 - 3];
    f32x4 s0a = {a0.x, a1.x, a2.x, a3.x}, s1a = {a0.y, a1.y, a2.y, a3.y};
    f32x4 s0b = {c0.x, c1.x, c2.x, c3.x}, s1b = {c0.y, c1.y, c2.y, c3.y};

    const ushort* sk = &sK[kt & 1][0];
    const ushort* sv = &sV[kt & 1][0];
    short8 kf0 = *(const short8*)(sk + kOff0);
    short8 kf1 = *(const short8*)(sk + kOff1);
    short8 kf2 = *(const short8*)(sk + 1024 + kOff0);
    short8 kf3 = *(const short8*)(sk + 1024 + kOff1);
    s0a = __builtin_amdgcn_mfma_f32_16x16x32_bf16(qf0a, kf0, s0a, 0, 0, 0);
    s0a = __builtin_amdgcn_mfma_f32_16x16x32_bf16(qf1a, kf1, s0a, 0, 0, 0);
    s1a = __builtin_amdgcn_mfma_f32_16x16x32_bf16(qf0a, kf2, s1a, 0, 0, 0);
    s1a = __builtin_amdgcn_mfma_f32_16x16x32_bf16(qf1a, kf3, s1a, 0, 0, 0);
    s0b = __builtin_amdgcn_mfma_f32_16x16x32_bf16(qf0b, kf0, s0b, 0, 0, 0);
    s0b = __builtin_amdgcn_mfma_f32_16x16x32_bf16(qf1b, kf1, s0b, 0, 0, 0);
    s1b = __builtin_amdgcn_mfma_f32_16x16x32_bf16(qf0b, kf2, s1b, 0, 0, 0);
    s1b = __builtin_amdgcn_mfma_f32_16x16x32_bf16(qf1b, kf3, s1b, 0, 0, 0);

#pragma unroll
    for (int r = 0; r < 4; ++r) {
      float p0 = __builtin_amdgcn_exp2f(s0a[r]);
      float p1 = __builtin_amdgcn_exp2f(s1a[r]);
      float u0 = __builtin_amdgcn_exp2f(s0b[r]);
      float u1 = __builtin_amdgcn_exp2f(s1b[r]);
      if (kt == 15) {
        bool m0v = (k0 + l16 < S_), m1v = (k0 + 16 + l16 < S_);
        p0 = m0v ? p0 : 0.f;  p1 = m1v ? p1 : 0.f;
        u0 = m0v ? u0 : 0.f;  u1 = m1v ? u1 : 0.f;
      }
      psA[r] += p0 + p1;
      psB[r] += u0 + u1;
      *(unsigned*)(sPw + (g4 * 4 + r) * 40 + 2 * l16)        = cvt_pk_bf16(p0, p1);
      *(unsigned*)(sPw + (16 + g4 * 4 + r) * 40 + 2 * l16)   = cvt_pk_bf16(u0, u1);
    }
    short8 pfA = *(const short8*)(sPw + l16 * 40 + 8 * g4);
    short8 pfB = *(const short8*)(sPw + (16 + l16) * 40 + 8 * g4);
#pragma unroll
    for (int nt = 0; nt < 4; ++nt) {
      short8 vf = *(const short8*)(sv + vOff + nt * 512);    // shared by both sub-tiles
      accA[nt] = __builtin_amdgcn_mfma_f32_16x16x32_bf16(pfA, vf, accA[nt], 0, 0, 0);
      accB[nt] = __builtin_amdgcn_mfma_f32_16x16x32_bf16(pfB, vf, accB[nt], 0, 0, 0);
    }
  }

#pragma unroll
  for (int off = 1; off < 16; off <<= 1) {
#pragma unroll
    for (int r = 0; r < 4; ++r) {
      psA[r] += __shfl_xor(psA[r], off, 64);
      psB[r] += __shfl_xor(psB[r], off, 64);
    }
  }

#pragma unroll
  for (int r = 0; r < 4; ++r) {
    int qa = qw + g4 * 4 + r;
    if (qa < S_) {
      float inv = 1.f / psA[r];
#pragma unroll
      for (int nt = 0; nt < 4; ++nt)
        ao[((size_t)b * S_ + qa) * 1024 + head * 64 + nt * 16 + l16] = f2bf(accA[nt][r] * inv);
    }
    int qb2 = qa + 16;
    if (qb2 < S_) {
      float inv = 1.f / psB[r];
#pragma unroll
      for (int nt = 0; nt < 4; ++nt)
        ao[((size_t)b * S_ + qb2) * 1024 + head * 64 + nt * 16 + l16] = f2bf(accB[nt][r] * inv);
    }
  }
}

extern "C" void kernel_launch(void* const* d_in, const int* in_sizes, int n_in,
                              void* d_out, int out_size, void* d_ws, size_t ws_size,
                              hipStream_t stream) {
  const float* query = (const float*)d_in[0];
  const float* key   = (const float*)d_in[1];
  const float* value = (const float*)d_in[2];
  const float* Wq    = (const float*)d_in[3];
  const float* Wk    = (const float*)d_in[4];
  const float* Wv    = (const float*)d_in[5];
  const float* Wo    = (const float*)d_in[6];
  const float* rel   = (const float*)d_in[7];

  char* ws = (char*)d_ws;
  size_t off = 0;
  auto alloc = [&](size_t bytes) { char* p = ws + off; off += (bytes + 255) & ~(size_t)255; return p; };

  const size_t MEelems = (size_t)M_ * E_;             // 15,859,712
  ushort* qb  = (ushort*)alloc(MEelems * 2);          // query in bf16
  ushort* wqT = (ushort*)alloc((size_t)1024 * 1024 * 2);
  ushort* wkT = (ushort*)alloc((size_t)256 * 1024 * 2);   // contiguous with wvT:
  ushort* wvT = (ushort*)alloc((size_t)256 * 1024 * 2);   // [wkT; wvT] = 512x1024 B matrix
  ushort* woT = (ushort*)alloc((size_t)1024 * 1024 * 2);
  ushort* qp  = (ushort*)alloc((size_t)B_ * NH * SP * 64 * 2);   // 32 MB
  ushort* kp  = (ushort*)alloc((size_t)B_ * 4 * SP * 64 * 2);    // 8 MB
  ushort* vp  = (ushort*)alloc((size_t)B_ * 4 * 64 * SP * 2);    // 8 MB
  ushort* ao  = (ushort*)alloc(MEelems * 2);
  (void)wvT;

  prep_all<<<4608, 256, 0, stream>>>(Wq, Wk, Wv, Wo, wqT, wkT, wvT, woT,
                                     query, qb, (int)(MEelems / 4));

  const float QSCALE = 0.125f * 1.44269504f;   // fold 1/sqrt(D) and log2e into q
  gemm_cnt256<0><<<244, 512, 0, stream>>>(qb, wqT, qp, QSCALE);
  kvproj256<<<244, 512, 0, stream>>>(key, value, wkT, kp, vp);

  attn_kernel<<<2048, 256, 0, stream>>>(qp, kp, vp, rel, ao);

  gemm_cnt256<2><<<244, 512, 0, stream>>>(ao, woT, d_out, 1.0f);
}